// Round 11
// baseline (523.587 us; speedup 1.0000x reference)
//
#include <hip/hip_runtime.h>
#include <math.h>

#define N_BOX 8192
#define NW 128              // 8192 / 64 words
#define NBLK 16             // blocks (1 per CU, trivially co-resident on 256 CUs)
#define LCAP 24576          // edges staged in LDS (96 KiB)
#define ECAP_MAX (1 << 21)  // max edges in global buffer (8 MiB)
#define THR_C 0.7f
#define IOU_THR_C 0.5f
#define EPS_C 1e-9f

// SCALER = max(3508/1280, 2480/1280) computed in double then rounded to f32,
// matching numpy/jax float32 weak-typed scalar promotion.
__device__ __constant__ float kScaler = (float)(3508.0 / 1280.0);

static __device__ __forceinline__ unsigned long long make_key(const float* conf, int i) {
    float c0 = conf[2 * i], c1 = conf[2 * i + 1];
    bool valid = (c0 > THR_C) || (c1 > THR_C);
    float ms = valid ? fmaxf(c0, c1) : -INFINITY;
    unsigned int u = __float_as_uint(ms);
    unsigned int m = (u & 0x80000000u) ? ~u : (u | 0x80000000u); // ascending map
    unsigned int d = ~m;                                          // descending key
    return ((unsigned long long)d << 32) | (unsigned int)i;
}

// ---------------------------------------------------------------------------
// 16-block barrier. Epochs 1..4 are unique per launch and never equal the
// 0xAAAAAAAA ws-poison, so no counter reset is needed. Arriving block: fence
// (publish writes: block is on one CU -> one XCD L2, thread-0 fence flushes
// it) + atomicExch flag. Block 0: 15 threads poll the 15 flags in parallel,
// then release; all blocks fence after the synchronizing read (acquire).
// Device-scope atomics are cross-XCD coherent (G12/G16).
// ---------------------------------------------------------------------------
static __device__ __forceinline__ void gbar(int* flags, int* release, int epoch) {
    __syncthreads();
    if (threadIdx.x == 0) __threadfence();        // publish this block's writes
    __syncthreads();
    if (blockIdx.x == 0) {
        int tt = threadIdx.x;
        if (tt > 0 && tt < NBLK)
            while (atomicAdd(&flags[tt], 0) != epoch) { }
        __syncthreads();                          // all flags seen
        if (tt == 0) { atomicExch(release, epoch); __threadfence(); }
    } else {
        if (threadIdx.x == 0) {
            atomicExch(&flags[blockIdx.x], epoch);
            while (atomicAdd(release, 0) != epoch) { }
            __threadfence();                      // acquire: invalidate stale
        }
    }
    __syncthreads();
}

// LDS overlay: phases are separated by barriers, so one union serves all.
union SMem {
    unsigned long long sortbuf[N_BOX];            // 64 KiB (S1 uses first 2048)
    struct { float4 cb[64]; float carea[64]; } p; // pair tile
    struct {
        unsigned int eL[LCAP];                    // 96 KiB
        unsigned long long kL[NW], tL[NW], vL[NW];
        int chg[3];
    } j;                                          // ~99 KiB
};

// ---------------------------------------------------------------------------
// One plain-launch kernel, 16 blocks x 1024 threads, 4 custom barriers.
// Phases (verified in rounds 8-10, code unchanged):
//   S1: blocks 0-3 bitonic-sort 2048-chunks (global-index directions).
//   S2: blocks 0-1 fused k=4096 + k=8192 merge + gather (sb/order/validw/nv).
//   P : 16 blocks build the compact edge list over the nv x nv triangle.
//   J : block 0 Jacobi-iterates to the greedy-NMS fixpoint (unique fixpoint,
//       certified by k_new==k_old); overflow -> serial on-the-fly greedy.
//   O : blocks 0-7 write the (N,6) output.
// ---------------------------------------------------------------------------
__global__ __launch_bounds__(1024) void mega_kernel(
        const float* __restrict__ conf,
        const float* __restrict__ bboxes,
        unsigned long long* __restrict__ keys,
        float4* __restrict__ sb,
        unsigned int* __restrict__ order,
        unsigned long long* __restrict__ validw,
        int* __restrict__ ecntE,
        int* __restrict__ nvD,
        unsigned int* __restrict__ edges,
        unsigned long long* __restrict__ keepK,
        int* __restrict__ flags,
        int* __restrict__ release,
        float* __restrict__ out,
        int ecap) {
    __shared__ SMem sm;
    int bid = blockIdx.x;
    int t = threadIdx.x;
    int lane = t & 63;

    // ---------------- Phase S1: 4 blocks sort 2048-chunks ----------------
    if (bid == 0 && t == 0) { atomicExch(ecntE, 0); atomicExch(nvD, 0); }
    if (bid < 4) {
        int base = bid * 2048;
        for (int l = t; l < 2048; l += 1024) sm.sortbuf[l] = make_key(conf, base + l);
        __syncthreads();
        for (int k = 2; k <= 2048; k <<= 1) {
            for (int j = k >> 1; j > 0; j >>= 1) {
                int i = ((t & ~(j - 1)) << 1) | (t & (j - 1));
                int p = i | j;
                bool up = (((base + i) & k) == 0);
                unsigned long long a = sm.sortbuf[i], b = sm.sortbuf[p];
                bool sw = up ? (a > b) : (a < b);
                if (sw) { sm.sortbuf[i] = b; sm.sortbuf[p] = a; }
                __syncthreads();
            }
        }
        for (int l = t; l < 2048; l += 1024) keys[base + l] = sm.sortbuf[l];
    }
    gbar(flags, release, 1);

    // ------- Phase S2: 2 blocks, fused k=4096 + k=8192 merge + gather -----
    if (bid < 2) {
        int half = bid;
        int base = half << 12;
        for (int l = t; l < 8192; l += 1024) sm.sortbuf[l] = keys[l];
        __syncthreads();
        // k=4096 merge on the full array
        for (int j = 2048; j > 0; j >>= 1) {
            for (int t2 = t; t2 < 4096; t2 += 1024) {
                int i = ((t2 & ~(j - 1)) << 1) | (t2 & (j - 1));
                int p = i | j;
                bool up = ((i & 4096) == 0);
                unsigned long long a = sm.sortbuf[i], b = sm.sortbuf[p];
                bool sw = up ? (a > b) : (a < b);
                if (sw) { sm.sortbuf[i] = b; sm.sortbuf[p] = a; }
            }
            __syncthreads();
        }
        // k=8192, j=4096: min -> low half, max -> high half (all ascending)
        unsigned long long v4[4];
#pragma unroll
        for (int q = 0; q < 4; ++q) {
            int l = t + (q << 10);
            unsigned long long a = sm.sortbuf[l], b = sm.sortbuf[l + 4096];
            v4[q] = half ? (a > b ? a : b) : (a > b ? b : a);
        }
        __syncthreads();
#pragma unroll
        for (int q = 0; q < 4; ++q) sm.sortbuf[base + t + (q << 10)] = v4[q];
        __syncthreads();
        // j=2048..1 on own half (all ascending at k=8192)
        for (int j = 2048; j > 0; j >>= 1) {
            for (int t2 = t; t2 < 2048; t2 += 1024) {
                int i = base + (((t2 & ~(j - 1)) << 1) | (t2 & (j - 1)));
                int p = i | j;
                unsigned long long a = sm.sortbuf[i], b = sm.sortbuf[p];
                if (a > b) { sm.sortbuf[i] = b; sm.sortbuf[p] = a; }
            }
            __syncthreads();
        }
        // gather: sb/order/validw; nv accumulated (valid boxes = ranks [0,nv))
        for (int l = t; l < 4096; l += 1024) {
            int gi = base + l;
            unsigned int o = (unsigned int)(sm.sortbuf[gi] & 0xffffffffull);
            order[gi] = o;
            sb[gi] = ((const float4*)bboxes)[o];
            float c0 = conf[2 * o], c1 = conf[2 * o + 1];
            unsigned long long vb = __ballot((c0 > THR_C) || (c1 > THR_C));
            if ((gi & 63) == 0) {
                validw[gi >> 6] = vb;
                atomicAdd(nvD, __popcll(vb));
            }
        }
    }
    gbar(flags, release, 2);

    // --------- Phase P: 16 blocks build edge list over nv triangle --------
    {
        int nv = atomicAdd(nvD, 0);
        for (int tile = bid; tile < 8 * 128; tile += NBLK) {
            int iblk = tile & 7;             // 8 i-tiles of 1024 rows
            int w = tile >> 3;               // 128 j-tiles of 64 cols
            int ibase = iblk << 10, jbase = w << 6;
            if (ibase >= nv || jbase >= nv || jbase + 63 <= ibase) continue; // uniform
            if (t < 64) {
                float4 c = sb[jbase + t];
                sm.p.cb[t] = c;
                sm.p.carea[t] = (c.z - c.x) * (c.w - c.y);
            }
            __syncthreads();
            int i = ibase + t;
            unsigned long long bits = 0ull;
            if (i < nv && jbase + 63 > i) {
                float4 r = sb[i];
                float ra = (r.z - r.x) * (r.w - r.y);
#pragma unroll 8
                for (int b = 0; b < 64; ++b) {
                    float4 c = sm.p.cb[b];
                    float iw = fminf(r.z, c.z) - fmaxf(r.x, c.x);
                    float ih = fminf(r.w, c.w) - fmaxf(r.y, c.y);
                    iw = fmaxf(iw, 0.0f);
                    ih = fmaxf(ih, 0.0f);
                    float inter = iw * ih;
                    float iou = inter / (ra + sm.p.carea[b] - inter + EPS_C);
                    if ((iou > IOU_THR_C) && ((jbase + b) > i)) bits |= (1ull << b);
                }
            }
            // drop invalid targets (ranks >= nv can never be kept)
            unsigned long long tmask = (jbase + 64 <= nv) ? ~0ull
                                       : ((1ull << (nv - jbase)) - 1ull);
            unsigned long long ebits = bits & tmask;
            int ec = __popcll(ebits);
            int pre = ec;
#pragma unroll
            for (int d = 1; d < 64; d <<= 1) {
                int vv = __shfl_up(pre, d, 64);
                if (lane >= d) pre += vv;
            }
            int tot = __shfl(pre, 63, 64);
            if (tot > 0) {
                int ebase = 0;
                if (lane == 63) ebase = atomicAdd(ecntE, tot);
                ebase = __shfl(ebase, 63, 64);
                int idx = ebase + pre - ec;
                unsigned long long tb = ebits;
                while (tb) {
                    int b = __builtin_ctzll(tb); tb &= tb - 1;
                    if (idx < ecap)
                        edges[idx] = ((unsigned int)i << 13) | (unsigned int)(jbase + b);
                    ++idx;
                }
            }
            __syncthreads();   // before next tile reuses cb
        }
    }
    gbar(flags, release, 3);

    // ---------- Phase J: block 0 Jacobi fixpoint (greedy NMS) -------------
    if (bid == 0) {
        int cnt = atomicAdd(ecntE, 0);
        if (t < NW) { unsigned long long v = validw[t]; sm.j.vL[t] = v; sm.j.kL[t] = v; }
        if (t == 0) { sm.j.chg[0] = 0; sm.j.chg[1] = 0; sm.j.chg[2] = 0; }
        if (cnt <= ecap) {
            int lim = cnt < LCAP ? cnt : LCAP;
            for (int e = t; e < lim; e += 1024) sm.j.eL[e] = edges[e];
        }
        __syncthreads();
        if (cnt <= ecap) {
            for (int it = 0; it < N_BOX; ++it) {
                if (t < NW) sm.j.tL[t] = 0ull;
                __syncthreads();
                for (int e = t; e < cnt; e += 1024) {
                    unsigned int ed = (e < LCAP) ? sm.j.eL[e] : edges[e];
                    int src = (int)(ed >> 13);
                    if ((sm.j.kL[src >> 6] >> (src & 63)) & 1ull) {
                        int tg = (int)(ed & 8191u);
                        atomicOr(&sm.j.tL[tg >> 6], 1ull << (tg & 63));
                    }
                }
                __syncthreads();
                if (t < NW) {
                    unsigned long long nk = sm.j.vL[t] & ~sm.j.tL[t];
                    if (nk != sm.j.kL[t]) sm.j.chg[it % 3] = 1;
                    sm.j.kL[t] = nk;
                }
                if (t == 0) sm.j.chg[(it + 2) % 3] = 0; // reset 2 barriers early
                __syncthreads();
                if (sm.j.chg[it % 3] == 0) break;       // uniform after barrier
            }
        } else {
            // fallback: serial greedy, IoU recomputed on the fly (one wave)
            if (t < NW) sm.j.tL[t] = ~sm.j.vL[t];
            __syncthreads();
            if (t < 64) {
                for (int i = 0; i < N_BOX - 1; ++i) {
                    bool kept = !((sm.j.tL[i >> 6] >> (i & 63)) & 1ull);
                    if (kept) {
                        float4 r = sb[i];
                        float ra = (r.z - r.x) * (r.w - r.y);
                        for (int jj = i + 1 + lane; jj < N_BOX; jj += 64) {
                            float4 c = sb[jj];
                            float ca = (c.z - c.x) * (c.w - c.y);
                            float iw = fminf(r.z, c.z) - fmaxf(r.x, c.x);
                            float ih = fminf(r.w, c.w) - fmaxf(r.y, c.y);
                            iw = fmaxf(iw, 0.0f);
                            ih = fmaxf(ih, 0.0f);
                            float inter = iw * ih;
                            float iou = inter / (ra + ca - inter + EPS_C);
                            if (iou > IOU_THR_C)
                                atomicOr(&sm.j.tL[jj >> 6], 1ull << (jj & 63));
                        }
                    }
                }
            }
            __syncthreads();
            if (t < NW) sm.j.kL[t] = sm.j.vL[t] & ~sm.j.tL[t];
            __syncthreads();
        }
        if (t < NW) keepK[t] = sm.j.kL[t];
    }
    gbar(flags, release, 4);

    // ---------- Phase O: blocks 0-7 write (N,6) output --------------------
    if (bid < 8) {
        int i = bid * 1024 + t;
        float kf = ((keepK[i >> 6] >> (i & 63)) & 1ull) ? 1.0f : 0.0f;
        float4 b = sb[i];
        unsigned int o = order[i];
        float s = kScaler * kf;
        out[i * 6 + 0] = b.x * s;
        out[i * 6 + 1] = b.y * s;
        out[i * 6 + 2] = b.z * s;
        out[i * 6 + 3] = b.w * s;
        out[i * 6 + 4] = conf[2 * o] * kf;
        out[i * 6 + 5] = conf[2 * o + 1] * kf;
    }
}

extern "C" void kernel_launch(void* const* d_in, const int* in_sizes, int n_in,
                              void* d_out, int out_size, void* d_ws, size_t ws_size,
                              hipStream_t stream) {
    const float* cls_conf = (const float*)d_in[0];   // (8192, 2)
    const float* bboxes   = (const float*)d_in[1];   // (8192, 4)
    float* out = (float*)d_out;                      // (8192, 6)

    char* ws = (char*)d_ws;
    unsigned long long* keys   = (unsigned long long*)(ws + 0);        //  64 KiB
    float4*             sb     = (float4*)(ws + 65536);                // 128 KiB
    unsigned int*       order  = (unsigned int*)(ws + 196608);         //  32 KiB
    unsigned long long* validw = (unsigned long long*)(ws + 229376);   //   1 KiB
    int*                ecntE  = (int*)(ws + 230400);                  //   4 B
    int*                nvD    = (int*)(ws + 230408);                  //   4 B
    unsigned long long* keepK  = (unsigned long long*)(ws + 230912);   //   1 KiB
    int*                flags  = (int*)(ws + 231936);                  //  64 B
    int*                release= (int*)(ws + 232064);                  //   4 B
    const size_t EDGE_OFF = 237568;
    unsigned int*       edges  = (unsigned int*)(ws + EDGE_OFF);
    size_t avail = (ws_size > EDGE_OFF + 16) ? (ws_size - EDGE_OFF) / 4 : 0;
    int ecap = (int)(avail > (size_t)ECAP_MAX ? (size_t)ECAP_MAX : avail);

    mega_kernel<<<NBLK, 1024, 0, stream>>>(cls_conf, bboxes, keys, sb, order,
                                           validw, ecntE, nvD, edges, keepK,
                                           flags, release, out, ecap);
}

// Round 12
// 136.815 us; speedup vs baseline: 3.8270x; 3.8270x over previous
//
#include <hip/hip_runtime.h>
#include <math.h>

#define N_BOX 8192
#define NW 128              // 8192 / 64 words
#define LCAP 24576          // edges staged in LDS (96 KiB)
#define ECAP_MAX (1 << 21)  // max edges in global buffer (8 MiB)
#define THR_C 0.7f
#define IOU_THR_C 0.5f
#define EPS_C 1e-9f

// SCALER = max(3508/1280, 2480/1280) computed in double then rounded to f32,
// matching numpy/jax float32 weak-typed scalar promotion.
__device__ __constant__ float kScaler = (float)(3508.0 / 1280.0);

static __device__ __forceinline__ unsigned long long make_key(const float* conf, int i) {
    float c0 = conf[2 * i], c1 = conf[2 * i + 1];
    bool valid = (c0 > THR_C) || (c1 > THR_C);
    float ms = valid ? fmaxf(c0, c1) : -INFINITY;
    unsigned int u = __float_as_uint(ms);
    unsigned int m = (u & 0x80000000u) ? ~u : (u | 0x80000000u); // ascending map
    unsigned int d = ~m;                                          // descending key
    return ((unsigned long long)d << 32) | (unsigned int)i;
}

// ---------------------------------------------------------------------------
// Sort stage 1: 4 blocks x 2048 elements, all k<=2048 passes LDS-local.
// Directions use GLOBAL indices -> network identical to the verified
// single-block bitonic sort. Block 0 also zero-inits the global counters.
// ---------------------------------------------------------------------------
__global__ __launch_bounds__(1024) void sort_local1(const float* __restrict__ conf,
                                                    unsigned long long* __restrict__ keys,
                                                    int* __restrict__ ecntE,
                                                    int* __restrict__ nvD) {
    __shared__ unsigned long long s[2048];
    int base = blockIdx.x * 2048;
    if (blockIdx.x == 0 && threadIdx.x == 0) { *ecntE = 0; *nvD = 0; }
    for (int l = threadIdx.x; l < 2048; l += 1024) s[l] = make_key(conf, base + l);
    __syncthreads();
    for (int k = 2; k <= 2048; k <<= 1) {
        for (int j = k >> 1; j > 0; j >>= 1) {
            int t = threadIdx.x;
            int i = ((t & ~(j - 1)) << 1) | (t & (j - 1));
            int p = i | j;
            bool up = (((base + i) & k) == 0);
            unsigned long long a = s[i], b = s[p];
            bool sw = up ? (a > b) : (a < b);
            if (sw) { s[i] = b; s[p] = a; }
            __syncthreads();
        }
    }
    for (int l = threadIdx.x; l < 2048; l += 1024) keys[base + l] = s[l];
}

// ---------------------------------------------------------------------------
// Sort stage 2 (fused k=4096 + k=8192) + gather. Each of 2 blocks loads ALL
// 8192 keys, runs the k=4096 merge phases on the full array in LDS, then the
// k=8192 j=4096 cross exchange for its own half, then j=2048..1 locally (all
// ascending), then consumes the sorted half directly from LDS: writes
// sb/order/validw and accumulates nv (valid boxes occupy ranks [0, nv)).
// ---------------------------------------------------------------------------
__global__ __launch_bounds__(1024) void sort_final2(const unsigned long long* __restrict__ keys,
                                                    const float* __restrict__ bboxes,
                                                    const float* __restrict__ conf,
                                                    float4* __restrict__ sb,
                                                    unsigned int* __restrict__ order,
                                                    unsigned long long* __restrict__ validw,
                                                    int* __restrict__ nvD) {
    __shared__ unsigned long long s[8192];   // 64 KiB
    int half = blockIdx.x;                   // 0 or 1
    int base = half << 12;
    int t = threadIdx.x;
    for (int l = t; l < 8192; l += 1024) s[l] = keys[l];
    __syncthreads();
    // k=4096 merge on the full array
    for (int j = 2048; j > 0; j >>= 1) {
        for (int t2 = t; t2 < 4096; t2 += 1024) {
            int i = ((t2 & ~(j - 1)) << 1) | (t2 & (j - 1));
            int p = i | j;
            bool up = ((i & 4096) == 0);
            unsigned long long a = s[i], b = s[p];
            bool sw = up ? (a > b) : (a < b);
            if (sw) { s[i] = b; s[p] = a; }
        }
        __syncthreads();
    }
    // k=8192, j=4096: min -> low half, max -> high half (all ascending)
    unsigned long long v4[4];
#pragma unroll
    for (int q = 0; q < 4; ++q) {
        int l = t + (q << 10);
        unsigned long long a = s[l], b = s[l + 4096];
        v4[q] = half ? (a > b ? a : b) : (a > b ? b : a);
    }
    __syncthreads();
#pragma unroll
    for (int q = 0; q < 4; ++q) s[base + t + (q << 10)] = v4[q];
    __syncthreads();
    // j=2048..1 on own half (all ascending at k=8192)
    for (int j = 2048; j > 0; j >>= 1) {
        for (int t2 = t; t2 < 2048; t2 += 1024) {
            int i = base + (((t2 & ~(j - 1)) << 1) | (t2 & (j - 1)));
            int p = i | j;
            unsigned long long a = s[i], b = s[p];
            if (a > b) { s[i] = b; s[p] = a; }
        }
        __syncthreads();
    }
    for (int l = t; l < 4096; l += 1024) {
        int gi = base + l;
        unsigned int o = (unsigned int)(s[gi] & 0xffffffffull);
        order[gi] = o;
        sb[gi] = ((const float4*)bboxes)[o];
        float c0 = conf[2 * o], c1 = conf[2 * o + 1];
        unsigned long long vb = __ballot((c0 > THR_C) || (c1 > THR_C));
        if ((gi & 63) == 0) {
            validw[gi >> 6] = vb;
            atomicAdd(nvD, __popcll(vb));
        }
    }
}

// ---------------------------------------------------------------------------
// Kernel 3: pair kernel — compact edge list over the nv x nv upper triangle
// (valid boxes are exactly ranks [0,nv): invalid sort last with -inf keys).
// Edge = (src<<13)|tgt, both valid, iou > thr, tgt > src; exact IEEE fp32
// arithmetic identical to the reference. Wave-aggregated append.
// ---------------------------------------------------------------------------
__global__ void pair_kernel(const float4* __restrict__ sb,
                            const int* __restrict__ nvD,
                            unsigned int* __restrict__ edges,
                            int* __restrict__ ecntE,
                            int ecap) {
    int w = blockIdx.y;
    int jbase = w << 6;
    int ibase = blockIdx.x * 256;
    int nv = *nvD;
    if (ibase >= nv || jbase >= nv || jbase + 63 <= ibase) return;  // uniform
    __shared__ float4 cb[64];
    __shared__ float carea[64];
    if (threadIdx.x < 64) {
        float4 c = sb[jbase + threadIdx.x];
        cb[threadIdx.x] = c;
        carea[threadIdx.x] = (c.z - c.x) * (c.w - c.y);
    }
    __syncthreads();
    int i = ibase + threadIdx.x;
    unsigned long long bits = 0ull;
    if (i < nv && jbase + 63 > i) {
        float4 r = sb[i];
        float ra = (r.z - r.x) * (r.w - r.y);
#pragma unroll 8
        for (int b = 0; b < 64; ++b) {
            float4 c = cb[b];
            float iw = fminf(r.z, c.z) - fmaxf(r.x, c.x);
            float ih = fminf(r.w, c.w) - fmaxf(r.y, c.y);
            iw = fmaxf(iw, 0.0f);
            ih = fmaxf(ih, 0.0f);
            float inter = iw * ih;
            float iou = inter / (ra + carea[b] - inter + EPS_C);
            if ((iou > IOU_THR_C) && ((jbase + b) > i)) bits |= (1ull << b);
        }
    }
    // drop targets >= nv (invalid: can never be kept)
    unsigned long long tmask = (jbase + 64 <= nv) ? ~0ull
                               : ((1ull << (nv - jbase)) - 1ull);
    unsigned long long ebits = bits & tmask;
    int lane = threadIdx.x & 63;
    int ec = __popcll(ebits);
    int pre = ec;
#pragma unroll
    for (int d = 1; d < 64; d <<= 1) {
        int vv = __shfl_up(pre, d, 64);
        if (lane >= d) pre += vv;
    }
    int tot = __shfl(pre, 63, 64);
    if (tot > 0) {
        int base = 0;
        if (lane == 63) base = atomicAdd(ecntE, tot);
        base = __shfl(base, 63, 64);
        int idx = base + pre - ec;
        unsigned long long tb = ebits;
        while (tb) {
            int b = __builtin_ctzll(tb); tb &= tb - 1;
            if (idx < ecap) edges[idx] = ((unsigned int)i << 13) | (unsigned int)(jbase + b);
            ++idx;
        }
    }
}

// ---------------------------------------------------------------------------
// Kernel 4: Jacobi-iterated greedy NMS over the edge list + FUSED OUTPUT.
// Greedy NMS is the unique fixpoint of k[i] = v[i] & ~OR_{j<i,e(j,i)} k[j];
// Jacobi sweeps are exact for nodes of dependency depth <= t-1, so k_new ==
// k_old certifies convergence. Keep bits never leave LDS; the (N,6) output is
// written directly by this block (196 KB, ~3 µs single-CU — cheaper than a
// separate dispatch). Overflow (cnt > ecap, never expected) falls back to an
// on-the-fly serial greedy recomputing IoU from sb — slow but correct.
// ---------------------------------------------------------------------------
__global__ __launch_bounds__(1024) void scan_out_kernel(const unsigned int* __restrict__ edges,
                                                        const int* __restrict__ ecntE,
                                                        const unsigned long long* __restrict__ validw,
                                                        const float4* __restrict__ sb,
                                                        const unsigned int* __restrict__ order,
                                                        const float* __restrict__ conf,
                                                        float* __restrict__ out,
                                                        int ecap) {
    __shared__ unsigned int eL[LCAP];             // 96 KiB
    __shared__ unsigned long long kL[NW], tL[NW], vL[NW];
    __shared__ int chg[3];
    int t = threadIdx.x;
    int cnt = *ecntE;
    if (t < NW) { unsigned long long v = validw[t]; vL[t] = v; kL[t] = v; }
    if (t == 0) { chg[0] = 0; chg[1] = 0; chg[2] = 0; }
    if (cnt <= ecap) {
        int lim = cnt < LCAP ? cnt : LCAP;
        for (int e = t; e < lim; e += 1024) eL[e] = edges[e];
    }
    __syncthreads();
    if (cnt <= ecap) {
        for (int it = 0; it < N_BOX; ++it) {
            if (t < NW) tL[t] = 0ull;
            __syncthreads();
            for (int e = t; e < cnt; e += 1024) {
                unsigned int ed = (e < LCAP) ? eL[e] : edges[e];
                int src = (int)(ed >> 13);
                if ((kL[src >> 6] >> (src & 63)) & 1ull) {
                    int tg = (int)(ed & 8191u);
                    atomicOr(&tL[tg >> 6], 1ull << (tg & 63));
                }
            }
            __syncthreads();
            if (t < NW) {
                unsigned long long nk = vL[t] & ~tL[t];
                if (nk != kL[t]) chg[it % 3] = 1;
                kL[t] = nk;
            }
            if (t == 0) chg[(it + 2) % 3] = 0;   // reset 2 barriers before reuse
            __syncthreads();
            if (chg[it % 3] == 0) break;         // uniform: read after barrier
        }
    } else {
        // fallback: serial greedy, IoU recomputed on the fly (one wave)
        if (t < NW) tL[t] = ~vL[t];              // removed = !valid
        __syncthreads();
        if (t < 64) {
            int lane = t;
            for (int i = 0; i < N_BOX - 1; ++i) {
                bool kept = !((tL[i >> 6] >> (i & 63)) & 1ull);
                if (kept) {
                    float4 r = sb[i];
                    float ra = (r.z - r.x) * (r.w - r.y);
                    for (int j = i + 1 + lane; j < N_BOX; j += 64) {
                        float4 c = sb[j];
                        float ca = (c.z - c.x) * (c.w - c.y);
                        float iw = fminf(r.z, c.z) - fmaxf(r.x, c.x);
                        float ih = fminf(r.w, c.w) - fmaxf(r.y, c.y);
                        iw = fmaxf(iw, 0.0f);
                        ih = fmaxf(ih, 0.0f);
                        float inter = iw * ih;
                        float iou = inter / (ra + ca - inter + EPS_C);
                        if (iou > IOU_THR_C) atomicOr(&tL[j >> 6], 1ull << (j & 63));
                    }
                }
            }
        }
        __syncthreads();
        if (t < NW) kL[t] = vL[t] & ~tL[t];
    }
    __syncthreads();
    // fused output: [boxes*SCALER*kf, conf*kf]  (kL bit = KEEP)
    for (int i = t; i < N_BOX; i += 1024) {
        float kf = ((kL[i >> 6] >> (i & 63)) & 1ull) ? 1.0f : 0.0f;
        float4 b = sb[i];
        unsigned int o = order[i];
        float s = kScaler * kf;
        out[i * 6 + 0] = b.x * s;
        out[i * 6 + 1] = b.y * s;
        out[i * 6 + 2] = b.z * s;
        out[i * 6 + 3] = b.w * s;
        out[i * 6 + 4] = conf[2 * o] * kf;
        out[i * 6 + 5] = conf[2 * o + 1] * kf;
    }
}

extern "C" void kernel_launch(void* const* d_in, const int* in_sizes, int n_in,
                              void* d_out, int out_size, void* d_ws, size_t ws_size,
                              hipStream_t stream) {
    const float* cls_conf = (const float*)d_in[0];   // (8192, 2)
    const float* bboxes   = (const float*)d_in[1];   // (8192, 4)
    float* out = (float*)d_out;                      // (8192, 6)

    char* ws = (char*)d_ws;
    unsigned long long* keys   = (unsigned long long*)(ws + 0);        //  64 KiB
    float4*             sb     = (float4*)(ws + 65536);                // 128 KiB
    unsigned int*       order  = (unsigned int*)(ws + 196608);         //  32 KiB
    unsigned long long* validw = (unsigned long long*)(ws + 229376);   //   1 KiB
    int*                ecntE  = (int*)(ws + 230400);                  //   4 B
    int*                nvD    = (int*)(ws + 230408);                  //   4 B
    const size_t EDGE_OFF = 237568;
    unsigned int*       edges  = (unsigned int*)(ws + EDGE_OFF);
    size_t avail = (ws_size > EDGE_OFF + 16) ? (ws_size - EDGE_OFF) / 4 : 0;
    int ecap = (int)(avail > (size_t)ECAP_MAX ? (size_t)ECAP_MAX : avail);

    sort_local1<<<4, 1024, 0, stream>>>(cls_conf, keys, ecntE, nvD);
    sort_final2<<<2, 1024, 0, stream>>>(keys, bboxes, cls_conf, sb, order, validw, nvD);
    pair_kernel<<<dim3(32, 128), 256, 0, stream>>>(sb, nvD, edges, ecntE, ecap);
    scan_out_kernel<<<1, 1024, 0, stream>>>(edges, ecntE, validw, sb, order,
                                            cls_conf, out, ecap);
}